// Round 5
// baseline (636.077 us; speedup 1.0000x reference)
//
#include <hip/hip_runtime.h>
#include <hip/hip_bf16.h>
#include <cstddef>

#define CH 128
#define BN_EPS 1e-5f

typedef __bf16 bf16x8 __attribute__((ext_vector_type(8)));
typedef __bf16 bf16x4 __attribute__((ext_vector_type(4)));
typedef float  f32x4  __attribute__((ext_vector_type(4)));

__device__ inline float bf2f(__bf16 b) { return (float)b; }

// ---------------------------------------------------------------------------
// R5: stats_kernel rebuilt. R4's version: 784 blocks, rolled loop, 1 load in
// flight/thread -> 88us @ 580 GB/s effective (latency-bound, VALUBusy 1%).
// New: grid-stride float4 over N*32 elems, 1280 blocks, manual x4 unroll
// (4 independent 16B loads in flight). Everything else identical to R4.
// ---------------------------------------------------------------------------

__global__ void count_kernel(const int* __restrict__ dst, int* __restrict__ cnt,
                             int* __restrict__ slot, int E) {
    int e = blockIdx.x * 256 + threadIdx.x;
    if (e < E) slot[e] = atomicAdd(&cnt[dst[e]], 1);
}

__global__ void dinv_kernel(const int* __restrict__ cnt, float* __restrict__ dinv, int n) {
    int i = blockIdx.x * 256 + threadIdx.x;
    if (i < n) dinv[i] = rsqrtf((float)cnt[i] + 1.0f);  // +1 = self loop
}

__global__ __launch_bounds__(256) void scan1_kernel(const int* __restrict__ cnt,
                                                    int* __restrict__ offs,
                                                    int* __restrict__ bsum, int n) {
    __shared__ int sd[256];
    int t = threadIdx.x;
    int base = blockIdx.x * 1024 + t * 4;
    int v[4];
    #pragma unroll
    for (int j = 0; j < 4; ++j) v[j] = (base + j < n) ? cnt[base + j] : 0;
    int s = v[0] + v[1] + v[2] + v[3];
    sd[t] = s;
    __syncthreads();
    for (int off = 1; off < 256; off <<= 1) {
        int x = (t >= off) ? sd[t - off] : 0;
        __syncthreads();
        sd[t] += x;
        __syncthreads();
    }
    int run = sd[t] - s;
    #pragma unroll
    for (int j = 0; j < 4; ++j) {
        if (base + j < n) offs[base + j] = run;
        run += v[j];
    }
    if (t == 255) bsum[blockIdx.x] = sd[255];
}

__global__ __launch_bounds__(256) void scan2_kernel(int* __restrict__ bsum, int nb) {
    __shared__ int sd[256];
    int t = threadIdx.x;
    int base = t * 4;
    int v[4];
    #pragma unroll
    for (int j = 0; j < 4; ++j) v[j] = (base + j < nb) ? bsum[base + j] : 0;
    int s = v[0] + v[1] + v[2] + v[3];
    sd[t] = s;
    __syncthreads();
    for (int off = 1; off < 256; off <<= 1) {
        int x = (t >= off) ? sd[t - off] : 0;
        __syncthreads();
        sd[t] += x;
        __syncthreads();
    }
    int run = sd[t] - s;
    #pragma unroll
    for (int j = 0; j < 4; ++j) {
        if (base + j < nb) bsum[base + j] = run;
        run += v[j];
    }
}

__global__ void scan3_kernel(int* __restrict__ offs, const int* __restrict__ bsum,
                             int n, int E) {
    int i = blockIdx.x * 256 + threadIdx.x;
    if (i < n) offs[i] += bsum[i >> 10];
    if (i == 0) offs[n] = E;
}

__global__ void fill_kernel(const int* __restrict__ src, const int* __restrict__ dst,
                            const int* __restrict__ slot, const int* __restrict__ offs,
                            const float* __restrict__ dinv, int2* __restrict__ csr, int E) {
    int e = blockIdx.x * 256 + threadIdx.x;
    if (e >= E) return;
    int s = src[e], d = dst[e];
    int p = offs[d] + slot[e];
    float nrm = dinv[s] * dinv[d];
    csr[p] = make_int2(s, __float_as_int(nrm));
}

__global__ void wprep_kernel(const float* __restrict__ W, __bf16* __restrict__ Wb, int total) {
    int i = blockIdx.x * 256 + threadIdx.x;
    if (i < total) Wb[i] = (__bf16)W[i];
}

// ---------------------------------------------------------------------------
// Per-channel sum & sumsq. Grid-stride over total = N*32 float4s, manual x4
// unroll. Channel set per thread is loop-invariant: stride % 32 == 0.
// ---------------------------------------------------------------------------
__global__ __launch_bounds__(256) void stats_kernel(
    const float* __restrict__ in, const float* __restrict__ bias, int do_relu,
    float* __restrict__ sums, float* __restrict__ sumsq, int total) {
    int l = threadIdx.x & 31;
    int g = threadIdx.x >> 5;
    int c4 = l * 4;
    float4 bc = make_float4(0.f, 0.f, 0.f, 0.f);
    if (do_relu) bc = *(const float4*)&bias[c4];
    float4 s = make_float4(0.f, 0.f, 0.f, 0.f);
    float4 s2 = make_float4(0.f, 0.f, 0.f, 0.f);
    int gid = blockIdx.x * 256 + threadIdx.x;
    int gs = gridDim.x * 256;
    const float4* in4 = (const float4*)in;

    auto accum = [&](float4 v) {
        if (do_relu) {
            v.x = fmaxf(v.x + bc.x, 0.f); v.y = fmaxf(v.y + bc.y, 0.f);
            v.z = fmaxf(v.z + bc.z, 0.f); v.w = fmaxf(v.w + bc.w, 0.f);
        }
        s.x += v.x; s.y += v.y; s.z += v.z; s.w += v.w;
        s2.x += v.x * v.x; s2.y += v.y * v.y; s2.z += v.z * v.z; s2.w += v.w * v.w;
    };

    int i = gid;
    for (; i + 3 * gs < total; i += 4 * gs) {
        float4 v0 = in4[i];
        float4 v1 = in4[i + gs];
        float4 v2 = in4[i + 2 * gs];
        float4 v3 = in4[i + 3 * gs];
        accum(v0); accum(v1); accum(v2); accum(v3);
    }
    for (; i < total; i += gs) accum(in4[i]);

    __shared__ float4 ls[8][32], ls2[8][32];
    ls[g][l] = s; ls2[g][l] = s2;
    __syncthreads();
    if (g == 0) {
        #pragma unroll
        for (int k = 1; k < 8; ++k) {
            float4 a = ls[k][l], b = ls2[k][l];
            s.x += a.x; s.y += a.y; s.z += a.z; s.w += a.w;
            s2.x += b.x; s2.y += b.y; s2.z += b.z; s2.w += b.w;
        }
        unsafeAtomicAdd(&sums[c4 + 0], s.x);  unsafeAtomicAdd(&sums[c4 + 1], s.y);
        unsafeAtomicAdd(&sums[c4 + 2], s.z);  unsafeAtomicAdd(&sums[c4 + 3], s.w);
        unsafeAtomicAdd(&sumsq[c4 + 0], s2.x); unsafeAtomicAdd(&sumsq[c4 + 1], s2.y);
        unsafeAtomicAdd(&sumsq[c4 + 2], s2.z); unsafeAtomicAdd(&sumsq[c4 + 3], s2.w);
    }
}

__global__ void bnparam_kernel(const float* __restrict__ sums, const float* __restrict__ sumsq,
                               const float* __restrict__ gamma, const float* __restrict__ beta,
                               float* __restrict__ scale, float* __restrict__ shift, int n) {
    int c = threadIdx.x;
    if (c >= CH) return;
    float inv_n = 1.0f / (float)n;
    float mean = sums[c] * inv_n;
    float var  = sumsq[c] * inv_n - mean * mean;  // biased variance
    float sc = gamma[c] * rsqrtf(var + BN_EPS);
    scale[c] = sc;
    shift[c] = beta[c] - mean * sc;
}

// ---------------------------------------------------------------------------
// MFMA GEMM: H[row, j] = sum_k pre(A[row,k]) * W[j,k], H in bf16.
// ---------------------------------------------------------------------------
#define GROWS 64
#define LDA 136

__global__ __launch_bounds__(256) void gemm_mfma_kernel(
    const float* __restrict__ A, const float* __restrict__ bias, int do_relu,
    const float* __restrict__ scale, const float* __restrict__ shift,
    const __bf16* __restrict__ Wb, __bf16* __restrict__ Hout, int n) {
    __shared__ __bf16 As[GROWS][LDA];
    int tid = threadIdx.x;
    int row0 = blockIdx.x * GROWS;

    #pragma unroll
    for (int p = 0; p < 8; ++p) {
        int idx = p * 256 + tid;
        int r = idx >> 5;
        int f4 = idx & 31;
        int c4 = f4 * 4;
        int row = row0 + r;
        float4 v = make_float4(0.f, 0.f, 0.f, 0.f);
        if (row < n) v = ((const float4*)A)[(size_t)row * 32 + f4];
        float vv[4] = {v.x, v.y, v.z, v.w};
        __bf16 u[4];
        #pragma unroll
        for (int j = 0; j < 4; ++j) {
            int ch = c4 + j;
            float f = vv[j];
            if (do_relu) f = fmaxf(f + bias[ch], 0.f);
            f = f * scale[ch] + shift[ch];
            u[j] = (__bf16)f;
        }
        *(bf16x4*)&As[r][c4] = *(bf16x4*)u;
    }
    __syncthreads();

    int wv = tid >> 6;
    int lane = tid & 63;
    int m = lane & 15;
    int q = lane >> 4;
    int arow = wv * 16 + m;
    f32x4 acc[8] = {};
    #pragma unroll
    for (int kc = 0; kc < CH; kc += 32) {
        bf16x8 af = *(const bf16x8*)&As[arow][kc + q * 8];
        #pragma unroll
        for (int t = 0; t < 8; ++t) {
            bf16x8 bf = *(const bf16x8*)&Wb[(size_t)(t * 16 + m) * CH + kc + q * 8];
            acc[t] = __builtin_amdgcn_mfma_f32_16x16x32_bf16(af, bf, acc[t], 0, 0, 0);
        }
    }

    #pragma unroll
    for (int t = 0; t < 8; ++t) {
        #pragma unroll
        for (int r = 0; r < 4; ++r) {
            int row = row0 + wv * 16 + q * 4 + r;
            if (row < n) Hout[(size_t)row * CH + t * 16 + m] = (__bf16)acc[t][r];
        }
    }
}

// ---------------------------------------------------------------------------
// Gather aggregation: 16 lanes/node, 8 ch/lane (16B bf16x8 loads), 16 nodes
// per 256-thread block. Edge loop unrolled x4.
// ---------------------------------------------------------------------------
__global__ __launch_bounds__(256) void agg_gather_kernel(
    const __bf16* __restrict__ h, const int2* __restrict__ csr,
    const int* __restrict__ offs, const float* __restrict__ dinv,
    const float* __restrict__ bias, const float* __restrict__ x,
    float* __restrict__ outbuf, int n, int final_mode) {
    int node = blockIdx.x * 16 + (threadIdx.x >> 4);
    if (node >= n) return;
    int c = (threadIdx.x & 15) * 8;
    float di = dinv[node];
    float w0 = di * di;
    bf16x8 hv = *(const bf16x8*)&h[(size_t)node * CH + c];
    float a[8];
    #pragma unroll
    for (int j = 0; j < 8; ++j) a[j] = bf2f(hv[j]) * w0;

    int e = offs[node], end = offs[node + 1];
    for (; e + 4 <= end; e += 4) {
        int2 p0 = csr[e], p1 = csr[e + 1], p2 = csr[e + 2], p3 = csr[e + 3];
        bf16x8 v0 = *(const bf16x8*)&h[(size_t)p0.x * CH + c];
        bf16x8 v1 = *(const bf16x8*)&h[(size_t)p1.x * CH + c];
        bf16x8 v2 = *(const bf16x8*)&h[(size_t)p2.x * CH + c];
        bf16x8 v3 = *(const bf16x8*)&h[(size_t)p3.x * CH + c];
        float n0 = __int_as_float(p0.y), n1 = __int_as_float(p1.y);
        float n2 = __int_as_float(p2.y), n3 = __int_as_float(p3.y);
        #pragma unroll
        for (int j = 0; j < 8; ++j) {
            a[j] += bf2f(v0[j]) * n0;
            a[j] += bf2f(v1[j]) * n1;
            a[j] += bf2f(v2[j]) * n2;
            a[j] += bf2f(v3[j]) * n3;
        }
    }
    for (; e < end; ++e) {
        int2 p0 = csr[e];
        float n0 = __int_as_float(p0.y);
        bf16x8 v0 = *(const bf16x8*)&h[(size_t)p0.x * CH + c];
        #pragma unroll
        for (int j = 0; j < 8; ++j) a[j] += bf2f(v0[j]) * n0;
    }

    size_t o4 = (size_t)node * 32 + (c >> 2);
    if (final_mode) {
        float4 xb0 = ((const float4*)x)[o4];
        float4 xb1 = ((const float4*)x)[o4 + 1];
        float4 bb0 = *(const float4*)&bias[c];
        float4 bb1 = *(const float4*)&bias[c + 4];
        float4 o0, o1;
        o0.x = fmaxf(a[0] + bb0.x, 0.f) + xb0.x;
        o0.y = fmaxf(a[1] + bb0.y, 0.f) + xb0.y;
        o0.z = fmaxf(a[2] + bb0.z, 0.f) + xb0.z;
        o0.w = fmaxf(a[3] + bb0.w, 0.f) + xb0.w;
        o1.x = fmaxf(a[4] + bb1.x, 0.f) + xb1.x;
        o1.y = fmaxf(a[5] + bb1.y, 0.f) + xb1.y;
        o1.z = fmaxf(a[6] + bb1.z, 0.f) + xb1.z;
        o1.w = fmaxf(a[7] + bb1.w, 0.f) + xb1.w;
        ((float4*)outbuf)[o4] = o0;
        ((float4*)outbuf)[o4 + 1] = o1;
    } else {
        ((float4*)outbuf)[o4]     = make_float4(a[0], a[1], a[2], a[3]);
        ((float4*)outbuf)[o4 + 1] = make_float4(a[4], a[5], a[6], a[7]);
    }
}

extern "C" void kernel_launch(void* const* d_in, const int* in_sizes, int n_in,
                              void* d_out, int out_size, void* d_ws, size_t ws_size,
                              hipStream_t stream) {
    const float* x      = (const float*)d_in[0];
    const int*   eidx   = (const int*)d_in[1];
    const float* W1     = (const float*)d_in[2];
    const float* b1     = (const float*)d_in[3];
    const float* W2     = (const float*)d_in[4];
    const float* b2     = (const float*)d_in[5];
    const float* gamma1 = (const float*)d_in[6];
    const float* beta1  = (const float*)d_in[7];
    const float* gamma2 = (const float*)d_in[8];
    const float* beta2  = (const float*)d_in[9];
    float* out = (float*)d_out;

    const int N = in_sizes[0] / CH;
    const int E = in_sizes[1] / 2;
    const int* src = eidx;
    const int* dst = eidx + E;

    char* ws = (char*)d_ws;
    size_t off = 0;
    auto carve = [&](size_t bytes) { char* p = ws + off; off = (off + bytes + 1023) & ~(size_t)1023; return p; };
    int*    cnt     = (int*)carve((size_t)N * 4);
    float*  dinv    = (float*)carve((size_t)N * 4);
    int*    offs    = (int*)carve((size_t)(N + 1) * 4);
    int*    slot    = (int*)carve((size_t)E * 4);
    int*    bsum    = (int*)carve(1024 * 4);
    float*  small   = (float*)carve(8 * CH * 4);
    int2*   csr     = (int2*)carve((size_t)E * 8);
    __bf16* W1b     = (__bf16*)carve((size_t)CH * CH * 2);
    __bf16* W2b     = (__bf16*)carve((size_t)CH * CH * 2);
    __bf16* h_bf    = (__bf16*)carve((size_t)N * CH * 2);
    float*  agg_buf = (float*)carve((size_t)N * CH * 4);
    float* sums1  = small + 0 * CH;
    float* sumsq1 = small + 1 * CH;
    float* sums2  = small + 2 * CH;
    float* sumsq2 = small + 3 * CH;
    float* scale1 = small + 4 * CH;
    float* shift1 = small + 5 * CH;
    float* scale2 = small + 6 * CH;
    float* shift2 = small + 7 * CH;
    (void)ws_size; (void)n_in; (void)out_size;

    hipMemsetAsync(cnt, 0, (size_t)N * 4, stream);
    hipMemsetAsync(small, 0, 8 * CH * 4, stream);

    // ---- graph prep: degrees + slots + CSR + bf16 weights ----
    count_kernel<<<(E + 255) / 256, 256, 0, stream>>>(dst, cnt, slot, E);
    dinv_kernel<<<(N + 255) / 256, 256, 0, stream>>>(cnt, dinv, N);
    int nb = (N + 1023) / 1024;
    scan1_kernel<<<nb, 256, 0, stream>>>(cnt, offs, bsum, N);
    scan2_kernel<<<1, 256, 0, stream>>>(bsum, nb);
    scan3_kernel<<<(N + 255) / 256, 256, 0, stream>>>(offs, bsum, N, E);
    fill_kernel<<<(E + 255) / 256, 256, 0, stream>>>(src, dst, slot, offs, dinv, csr, E);
    wprep_kernel<<<(CH * CH + 255) / 256, 256, 0, stream>>>(W1, W1b, CH * CH);
    wprep_kernel<<<(CH * CH + 255) / 256, 256, 0, stream>>>(W2, W2b, CH * CH);

    // ---- stage 1 ----
    stats_kernel<<<1280, 256, 0, stream>>>(x, nullptr, 0, sums1, sumsq1, N * 32);
    bnparam_kernel<<<1, CH, 0, stream>>>(sums1, sumsq1, gamma1, beta1, scale1, shift1, N);
    gemm_mfma_kernel<<<(N + GROWS - 1) / GROWS, 256, 0, stream>>>(x, nullptr, 0, scale1, shift1, W1b, h_bf, N);
    agg_gather_kernel<<<(N + 15) / 16, 256, 0, stream>>>(h_bf, csr, offs, dinv,
                                                         nullptr, nullptr, agg_buf, N, 0);

    // ---- stage 2 ----
    stats_kernel<<<1280, 256, 0, stream>>>(agg_buf, b1, 1, sums2, sumsq2, N * 32);
    bnparam_kernel<<<1, CH, 0, stream>>>(sums2, sumsq2, gamma2, beta2, scale2, shift2, N);
    gemm_mfma_kernel<<<(N + GROWS - 1) / GROWS, 256, 0, stream>>>(agg_buf, b1, 1, scale2, shift2, W2b, h_bf, N);
    agg_gather_kernel<<<(N + 15) / 16, 256, 0, stream>>>(h_bf, csr, offs, dinv,
                                                         b2, x, out, N, 1);
}

// Round 6
// 426.258 us; speedup vs baseline: 1.4922x; 1.4922x over previous
//
#include <hip/hip_runtime.h>
#include <hip/hip_bf16.h>
#include <cstddef>

#define CH 128
#define BN_EPS 1e-5f
#define STATS_BLOCKS 1024

typedef __bf16 bf16x8 __attribute__((ext_vector_type(8)));
typedef __bf16 bf16x4 __attribute__((ext_vector_type(4)));
typedef float  f32x4  __attribute__((ext_vector_type(4)));

__device__ inline float bf2f(__bf16 b) { return (float)b; }

// ---------------------------------------------------------------------------
// R6: kill the same-address atomic chains in stats. R4/R5 evidence: stats dur
// scales with gridDim (784->88us, 1280->134us; ~93ns per same-address
// device-scope atomic, chain length == nblocks). New: block partials ->
// distinct rows (coalesced stores, no atomics), 16-block reduce_kernel with
// LDS tree writes sums||sumsq directly. Read loop keeps 4 loads in flight.
// ---------------------------------------------------------------------------

__global__ void count_kernel(const int* __restrict__ dst, int* __restrict__ cnt,
                             int* __restrict__ slot, int E) {
    int e = blockIdx.x * 256 + threadIdx.x;
    if (e < E) slot[e] = atomicAdd(&cnt[dst[e]], 1);
}

__global__ void dinv_kernel(const int* __restrict__ cnt, float* __restrict__ dinv, int n) {
    int i = blockIdx.x * 256 + threadIdx.x;
    if (i < n) dinv[i] = rsqrtf((float)cnt[i] + 1.0f);  // +1 = self loop
}

__global__ __launch_bounds__(256) void scan1_kernel(const int* __restrict__ cnt,
                                                    int* __restrict__ offs,
                                                    int* __restrict__ bsum, int n) {
    __shared__ int sd[256];
    int t = threadIdx.x;
    int base = blockIdx.x * 1024 + t * 4;
    int v[4];
    #pragma unroll
    for (int j = 0; j < 4; ++j) v[j] = (base + j < n) ? cnt[base + j] : 0;
    int s = v[0] + v[1] + v[2] + v[3];
    sd[t] = s;
    __syncthreads();
    for (int off = 1; off < 256; off <<= 1) {
        int x = (t >= off) ? sd[t - off] : 0;
        __syncthreads();
        sd[t] += x;
        __syncthreads();
    }
    int run = sd[t] - s;
    #pragma unroll
    for (int j = 0; j < 4; ++j) {
        if (base + j < n) offs[base + j] = run;
        run += v[j];
    }
    if (t == 255) bsum[blockIdx.x] = sd[255];
}

__global__ __launch_bounds__(256) void scan2_kernel(int* __restrict__ bsum, int nb) {
    __shared__ int sd[256];
    int t = threadIdx.x;
    int base = t * 4;
    int v[4];
    #pragma unroll
    for (int j = 0; j < 4; ++j) v[j] = (base + j < nb) ? bsum[base + j] : 0;
    int s = v[0] + v[1] + v[2] + v[3];
    sd[t] = s;
    __syncthreads();
    for (int off = 1; off < 256; off <<= 1) {
        int x = (t >= off) ? sd[t - off] : 0;
        __syncthreads();
        sd[t] += x;
        __syncthreads();
    }
    int run = sd[t] - s;
    #pragma unroll
    for (int j = 0; j < 4; ++j) {
        if (base + j < nb) bsum[base + j] = run;
        run += v[j];
    }
}

__global__ void scan3_kernel(int* __restrict__ offs, const int* __restrict__ bsum,
                             int n, int E) {
    int i = blockIdx.x * 256 + threadIdx.x;
    if (i < n) offs[i] += bsum[i >> 10];
    if (i == 0) offs[n] = E;
}

__global__ void fill_kernel(const int* __restrict__ src, const int* __restrict__ dst,
                            const int* __restrict__ slot, const int* __restrict__ offs,
                            const float* __restrict__ dinv, int2* __restrict__ csr, int E) {
    int e = blockIdx.x * 256 + threadIdx.x;
    if (e >= E) return;
    int s = src[e], d = dst[e];
    int p = offs[d] + slot[e];
    float nrm = dinv[s] * dinv[d];
    csr[p] = make_int2(s, __float_as_int(nrm));
}

__global__ void wprep_kernel(const float* __restrict__ W, __bf16* __restrict__ Wb, int total) {
    int i = blockIdx.x * 256 + threadIdx.x;
    if (i < total) Wb[i] = (__bf16)W[i];
}

// ---------------------------------------------------------------------------
// Per-channel sum & sumsq -> per-block partial row (256 floats: sums||sumsq).
// No global atomics. Grid-stride float4 loop, 4 independent loads in flight.
// ---------------------------------------------------------------------------
__global__ __launch_bounds__(256) void stats_kernel(
    const float* __restrict__ in, const float* __restrict__ bias, int do_relu,
    float* __restrict__ partials, int total) {
    int l = threadIdx.x & 31;
    int g = threadIdx.x >> 5;
    int c4 = l * 4;
    float4 bc = make_float4(0.f, 0.f, 0.f, 0.f);
    if (do_relu) bc = *(const float4*)&bias[c4];
    float4 s = make_float4(0.f, 0.f, 0.f, 0.f);
    float4 s2 = make_float4(0.f, 0.f, 0.f, 0.f);
    int gid = blockIdx.x * 256 + threadIdx.x;
    int gs = gridDim.x * 256;
    const float4* in4 = (const float4*)in;

    auto accum = [&](float4 v) {
        if (do_relu) {
            v.x = fmaxf(v.x + bc.x, 0.f); v.y = fmaxf(v.y + bc.y, 0.f);
            v.z = fmaxf(v.z + bc.z, 0.f); v.w = fmaxf(v.w + bc.w, 0.f);
        }
        s.x += v.x; s.y += v.y; s.z += v.z; s.w += v.w;
        s2.x += v.x * v.x; s2.y += v.y * v.y; s2.z += v.z * v.z; s2.w += v.w * v.w;
    };

    int i = gid;
    for (; i + 3 * gs < total; i += 4 * gs) {
        float4 v0 = in4[i];
        float4 v1 = in4[i + gs];
        float4 v2 = in4[i + 2 * gs];
        float4 v3 = in4[i + 3 * gs];
        accum(v0); accum(v1); accum(v2); accum(v3);
    }
    for (; i < total; i += gs) accum(in4[i]);

    __shared__ float4 ls[8][32], ls2[8][32];
    ls[g][l] = s; ls2[g][l] = s2;
    __syncthreads();
    if (g == 0) {
        #pragma unroll
        for (int k = 1; k < 8; ++k) {
            float4 a = ls[k][l], b = ls2[k][l];
            s.x += a.x; s.y += a.y; s.z += a.z; s.w += a.w;
            s2.x += b.x; s2.y += b.y; s2.z += b.z; s2.w += b.w;
        }
        // row layout: floats [0..127] = sums, [128..255] = sumsq
        ((float4*)partials)[blockIdx.x * 64 + l]      = s;
        ((float4*)partials)[blockIdx.x * 64 + 32 + l] = s2;
    }
}

// Fold R partial rows (256 floats each) -> out[256] (= sums||sumsq).
// 16 blocks: block j covers channels [j*16, j*16+16); 16 rows in parallel.
__global__ __launch_bounds__(256) void reduce_kernel(
    const float* __restrict__ partials, float* __restrict__ out, int R) {
    int t = threadIdx.x;
    int cl = t & 15;
    int r0 = t >> 4;
    int ch = blockIdx.x * 16 + cl;
    float acc = 0.f;
    for (int r = r0; r < R; r += 16) acc += partials[(size_t)r * 256 + ch];
    __shared__ float ls[256];
    ls[t] = acc;
    __syncthreads();
    #pragma unroll
    for (int off = 128; off >= 16; off >>= 1) {
        if (t < off) ls[t] += ls[t + off];
        __syncthreads();
    }
    if (t < 16) out[blockIdx.x * 16 + t] = ls[t];
}

__global__ void bnparam_kernel(const float* __restrict__ sums, const float* __restrict__ sumsq,
                               const float* __restrict__ gamma, const float* __restrict__ beta,
                               float* __restrict__ scale, float* __restrict__ shift, int n) {
    int c = threadIdx.x;
    if (c >= CH) return;
    float inv_n = 1.0f / (float)n;
    float mean = sums[c] * inv_n;
    float var  = sumsq[c] * inv_n - mean * mean;  // biased variance
    float sc = gamma[c] * rsqrtf(var + BN_EPS);
    scale[c] = sc;
    shift[c] = beta[c] - mean * sc;
}

// ---------------------------------------------------------------------------
// MFMA GEMM: H[row, j] = sum_k pre(A[row,k]) * W[j,k], H in bf16.
// ---------------------------------------------------------------------------
#define GROWS 64
#define LDA 136

__global__ __launch_bounds__(256) void gemm_mfma_kernel(
    const float* __restrict__ A, const float* __restrict__ bias, int do_relu,
    const float* __restrict__ scale, const float* __restrict__ shift,
    const __bf16* __restrict__ Wb, __bf16* __restrict__ Hout, int n) {
    __shared__ __bf16 As[GROWS][LDA];
    int tid = threadIdx.x;
    int row0 = blockIdx.x * GROWS;

    #pragma unroll
    for (int p = 0; p < 8; ++p) {
        int idx = p * 256 + tid;
        int r = idx >> 5;
        int f4 = idx & 31;
        int c4 = f4 * 4;
        int row = row0 + r;
        float4 v = make_float4(0.f, 0.f, 0.f, 0.f);
        if (row < n) v = ((const float4*)A)[(size_t)row * 32 + f4];
        float vv[4] = {v.x, v.y, v.z, v.w};
        __bf16 u[4];
        #pragma unroll
        for (int j = 0; j < 4; ++j) {
            int ch = c4 + j;
            float f = vv[j];
            if (do_relu) f = fmaxf(f + bias[ch], 0.f);
            f = f * scale[ch] + shift[ch];
            u[j] = (__bf16)f;
        }
        *(bf16x4*)&As[r][c4] = *(bf16x4*)u;
    }
    __syncthreads();

    int wv = tid >> 6;
    int lane = tid & 63;
    int m = lane & 15;
    int q = lane >> 4;
    int arow = wv * 16 + m;
    f32x4 acc[8] = {};
    #pragma unroll
    for (int kc = 0; kc < CH; kc += 32) {
        bf16x8 af = *(const bf16x8*)&As[arow][kc + q * 8];
        #pragma unroll
        for (int t = 0; t < 8; ++t) {
            bf16x8 bf = *(const bf16x8*)&Wb[(size_t)(t * 16 + m) * CH + kc + q * 8];
            acc[t] = __builtin_amdgcn_mfma_f32_16x16x32_bf16(af, bf, acc[t], 0, 0, 0);
        }
    }

    #pragma unroll
    for (int t = 0; t < 8; ++t) {
        #pragma unroll
        for (int r = 0; r < 4; ++r) {
            int row = row0 + wv * 16 + q * 4 + r;
            if (row < n) Hout[(size_t)row * CH + t * 16 + m] = (__bf16)acc[t][r];
        }
    }
}

// ---------------------------------------------------------------------------
// Gather aggregation: 16 lanes/node, 8 ch/lane (16B bf16x8 loads), 16 nodes
// per 256-thread block. Edge loop unrolled x4.
// ---------------------------------------------------------------------------
__global__ __launch_bounds__(256) void agg_gather_kernel(
    const __bf16* __restrict__ h, const int2* __restrict__ csr,
    const int* __restrict__ offs, const float* __restrict__ dinv,
    const float* __restrict__ bias, const float* __restrict__ x,
    float* __restrict__ outbuf, int n, int final_mode) {
    int node = blockIdx.x * 16 + (threadIdx.x >> 4);
    if (node >= n) return;
    int c = (threadIdx.x & 15) * 8;
    float di = dinv[node];
    float w0 = di * di;
    bf16x8 hv = *(const bf16x8*)&h[(size_t)node * CH + c];
    float a[8];
    #pragma unroll
    for (int j = 0; j < 8; ++j) a[j] = bf2f(hv[j]) * w0;

    int e = offs[node], end = offs[node + 1];
    for (; e + 4 <= end; e += 4) {
        int2 p0 = csr[e], p1 = csr[e + 1], p2 = csr[e + 2], p3 = csr[e + 3];
        bf16x8 v0 = *(const bf16x8*)&h[(size_t)p0.x * CH + c];
        bf16x8 v1 = *(const bf16x8*)&h[(size_t)p1.x * CH + c];
        bf16x8 v2 = *(const bf16x8*)&h[(size_t)p2.x * CH + c];
        bf16x8 v3 = *(const bf16x8*)&h[(size_t)p3.x * CH + c];
        float n0 = __int_as_float(p0.y), n1 = __int_as_float(p1.y);
        float n2 = __int_as_float(p2.y), n3 = __int_as_float(p3.y);
        #pragma unroll
        for (int j = 0; j < 8; ++j) {
            a[j] += bf2f(v0[j]) * n0;
            a[j] += bf2f(v1[j]) * n1;
            a[j] += bf2f(v2[j]) * n2;
            a[j] += bf2f(v3[j]) * n3;
        }
    }
    for (; e < end; ++e) {
        int2 p0 = csr[e];
        float n0 = __int_as_float(p0.y);
        bf16x8 v0 = *(const bf16x8*)&h[(size_t)p0.x * CH + c];
        #pragma unroll
        for (int j = 0; j < 8; ++j) a[j] += bf2f(v0[j]) * n0;
    }

    size_t o4 = (size_t)node * 32 + (c >> 2);
    if (final_mode) {
        float4 xb0 = ((const float4*)x)[o4];
        float4 xb1 = ((const float4*)x)[o4 + 1];
        float4 bb0 = *(const float4*)&bias[c];
        float4 bb1 = *(const float4*)&bias[c + 4];
        float4 o0, o1;
        o0.x = fmaxf(a[0] + bb0.x, 0.f) + xb0.x;
        o0.y = fmaxf(a[1] + bb0.y, 0.f) + xb0.y;
        o0.z = fmaxf(a[2] + bb0.z, 0.f) + xb0.z;
        o0.w = fmaxf(a[3] + bb0.w, 0.f) + xb0.w;
        o1.x = fmaxf(a[4] + bb1.x, 0.f) + xb1.x;
        o1.y = fmaxf(a[5] + bb1.y, 0.f) + xb1.y;
        o1.z = fmaxf(a[6] + bb1.z, 0.f) + xb1.z;
        o1.w = fmaxf(a[7] + bb1.w, 0.f) + xb1.w;
        ((float4*)outbuf)[o4] = o0;
        ((float4*)outbuf)[o4 + 1] = o1;
    } else {
        ((float4*)outbuf)[o4]     = make_float4(a[0], a[1], a[2], a[3]);
        ((float4*)outbuf)[o4 + 1] = make_float4(a[4], a[5], a[6], a[7]);
    }
}

extern "C" void kernel_launch(void* const* d_in, const int* in_sizes, int n_in,
                              void* d_out, int out_size, void* d_ws, size_t ws_size,
                              hipStream_t stream) {
    const float* x      = (const float*)d_in[0];
    const int*   eidx   = (const int*)d_in[1];
    const float* W1     = (const float*)d_in[2];
    const float* b1     = (const float*)d_in[3];
    const float* W2     = (const float*)d_in[4];
    const float* b2     = (const float*)d_in[5];
    const float* gamma1 = (const float*)d_in[6];
    const float* beta1  = (const float*)d_in[7];
    const float* gamma2 = (const float*)d_in[8];
    const float* beta2  = (const float*)d_in[9];
    float* out = (float*)d_out;

    const int N = in_sizes[0] / CH;
    const int E = in_sizes[1] / 2;
    const int* src = eidx;
    const int* dst = eidx + E;

    char* ws = (char*)d_ws;
    size_t off = 0;
    auto carve = [&](size_t bytes) { char* p = ws + off; off = (off + bytes + 1023) & ~(size_t)1023; return p; };
    int*    cnt      = (int*)carve((size_t)N * 4);
    float*  dinv     = (float*)carve((size_t)N * 4);
    int*    offs     = (int*)carve((size_t)(N + 1) * 4);
    int*    slot     = (int*)carve((size_t)E * 4);
    int*    bsum     = (int*)carve(1024 * 4);
    float*  small    = (float*)carve(8 * CH * 4);
    float*  partials = (float*)carve((size_t)STATS_BLOCKS * 256 * 4);
    int2*   csr      = (int2*)carve((size_t)E * 8);
    __bf16* W1b      = (__bf16*)carve((size_t)CH * CH * 2);
    __bf16* W2b      = (__bf16*)carve((size_t)CH * CH * 2);
    __bf16* h_bf     = (__bf16*)carve((size_t)N * CH * 2);
    float*  agg_buf  = (float*)carve((size_t)N * CH * 4);
    float* sums1  = small + 0 * CH;   // sums1||sumsq1 contiguous (reduce target)
    float* sumsq1 = small + 1 * CH;
    float* sums2  = small + 2 * CH;   // sums2||sumsq2 contiguous
    float* sumsq2 = small + 3 * CH;
    float* scale1 = small + 4 * CH;
    float* shift1 = small + 5 * CH;
    float* scale2 = small + 6 * CH;
    float* shift2 = small + 7 * CH;
    (void)ws_size; (void)n_in; (void)out_size;

    hipMemsetAsync(cnt, 0, (size_t)N * 4, stream);

    // ---- graph prep: degrees + slots + CSR + bf16 weights ----
    count_kernel<<<(E + 255) / 256, 256, 0, stream>>>(dst, cnt, slot, E);
    dinv_kernel<<<(N + 255) / 256, 256, 0, stream>>>(cnt, dinv, N);
    int nb = (N + 1023) / 1024;
    scan1_kernel<<<nb, 256, 0, stream>>>(cnt, offs, bsum, N);
    scan2_kernel<<<1, 256, 0, stream>>>(bsum, nb);
    scan3_kernel<<<(N + 255) / 256, 256, 0, stream>>>(offs, bsum, N, E);
    fill_kernel<<<(E + 255) / 256, 256, 0, stream>>>(src, dst, slot, offs, dinv, csr, E);
    wprep_kernel<<<(CH * CH + 255) / 256, 256, 0, stream>>>(W1, W1b, CH * CH);
    wprep_kernel<<<(CH * CH + 255) / 256, 256, 0, stream>>>(W2, W2b, CH * CH);

    // ---- stage 1 ----
    stats_kernel<<<STATS_BLOCKS, 256, 0, stream>>>(x, nullptr, 0, partials, N * 32);
    reduce_kernel<<<16, 256, 0, stream>>>(partials, sums1, STATS_BLOCKS);
    bnparam_kernel<<<1, CH, 0, stream>>>(sums1, sumsq1, gamma1, beta1, scale1, shift1, N);
    gemm_mfma_kernel<<<(N + GROWS - 1) / GROWS, 256, 0, stream>>>(x, nullptr, 0, scale1, shift1, W1b, h_bf, N);
    agg_gather_kernel<<<(N + 15) / 16, 256, 0, stream>>>(h_bf, csr, offs, dinv,
                                                         nullptr, nullptr, agg_buf, N, 0);

    // ---- stage 2 ----
    stats_kernel<<<STATS_BLOCKS, 256, 0, stream>>>(agg_buf, b1, 1, partials, N * 32);
    reduce_kernel<<<16, 256, 0, stream>>>(partials, sums2, STATS_BLOCKS);
    bnparam_kernel<<<1, CH, 0, stream>>>(sums2, sumsq2, gamma2, beta2, scale2, shift2, N);
    gemm_mfma_kernel<<<(N + GROWS - 1) / GROWS, 256, 0, stream>>>(agg_buf, b1, 1, scale2, shift2, W2b, h_bf, N);
    agg_gather_kernel<<<(N + 15) / 16, 256, 0, stream>>>(h_bf, csr, offs, dinv,
                                                         b2, x, out, N, 1);
}